// Round 1
// baseline (322.255 us; speedup 1.0000x reference)
//
#include <hip/hip_runtime.h>

#define B_ 4
#define N_ 2048
#define D_ 512
#define H_ 8
#define S_ (N_ + 1)          // 2049
#define SC 32                // s-rows per wsum chunk
#define NCH 65               // ceil(2049/32)
#define NB  260              // grid = NCH*B_; 8 waves/block, <=2 blocks/CU -> all co-resident

// workspace layout (float offsets)
#define BAR_OFF  0                                  // [32] grid-barrier line (uint at [0])
#define Q0_OFF   64                                 // [512]
#define TQ_OFF   1024                               // [H][D] = 4096
#define ATTN_OFF 8192                               // [B*H][S] = 65568
#define PW_OFF   81920                              // [NCH][B][H][D] = 1064960
#define PZ_OFF   (PW_OFF + NCH * B_ * H_ * D_)      // [NCH][B][H] = 2080
#define O0_OFF   (PZ_OFF + 2176)                    // [B][D]
#define Y_OFF    (O0_OFF + B_ * D_)                 // [B][D]

__device__ __forceinline__ float wave_reduce_sum(float v) {
    #pragma unroll
    for (int off = 32; off > 0; off >>= 1) v += __shfl_down(v, off, 64);
    return v;
}
__device__ __forceinline__ float wave_allreduce_sum(float v) {
    #pragma unroll
    for (int off = 1; off < 64; off <<= 1) v += __shfl_xor(v, off, 64);
    return v;
}
__device__ __forceinline__ float dot8(float4 a, float4 b, float4 c, float4 d) {
    return a.x*b.x + a.y*b.y + a.z*b.z + a.w*b.w
         + c.x*d.x + c.y*d.y + c.z*d.z + c.w*d.w;
}

// monotonic-counter grid barrier: release-add, acquire-load spin (agent scope).
// No reset -> no reset race; init kernel zeroes the counter each iteration.
__device__ __forceinline__ void grid_barrier(unsigned* bar, unsigned tgt) {
    __syncthreads();
    if (threadIdx.x == 0) {
        __threadfence();  // make this block's phase writes visible device-wide
        __hip_atomic_fetch_add(bar, 1u, __ATOMIC_RELEASE, __HIP_MEMORY_SCOPE_AGENT);
        while (__hip_atomic_load(bar, __ATOMIC_ACQUIRE, __HIP_MEMORY_SCOPE_AGENT) < tgt) {
            __builtin_amdgcn_s_sleep(1);
        }
    }
    __syncthreads();
}

__global__ void init_kernel(float* __restrict__ ws) {
    if (threadIdx.x < 32) ((unsigned*)ws)[BAR_OFF + threadIdx.x] = 0u;
}

__global__ void __launch_bounds__(512)
fused_kernel(const float* __restrict__ nf, const float* __restrict__ ct,
             const float* __restrict__ masks,
             const float* __restrict__ Wq, const float* __restrict__ bq,
             const float* __restrict__ Wk,
             const float* __restrict__ Wv, const float* __restrict__ bv,
             const float* __restrict__ Wo, const float* __restrict__ bo,
             const float* __restrict__ gamma, const float* __restrict__ beta,
             float* __restrict__ ws, float* __restrict__ out) {
    __shared__ float smem[544];          // union: q0s[64] | sa[8][32] | w[512]+z | ln r1/r2
    const int blk  = blockIdx.x;
    const int tid  = threadIdx.x;
    const int wv   = tid >> 6, lane = tid & 63;
    unsigned* bar  = (unsigned*)ws + BAR_OFF;
    unsigned  tgt  = NB;

    // ---- P1: q0[r] = Wq[r,:].ct + bq[r]   (blocks 0..63, one wave per row — proven K1 body)
    if (blk < 64) {
        int r = blk * 8 + wv;
        const float4* c4 = (const float4*)ct;
        float4 ca = c4[lane * 2], cb = c4[lane * 2 + 1];
        const float4* row = (const float4*)(Wq + (size_t)r * D_);
        float4 a = row[lane * 2], b = row[lane * 2 + 1];
        float acc = dot8(a, ca, b, cb);
        acc = wave_reduce_sum(acc);
        if (lane == 0) ws[Q0_OFF + r] = acc + bq[r];
    }
    grid_barrier(bar, tgt); tgt += NB;

    // ---- P2: tq[h,j] = sum_d q0[h*64+d] * Wk[h*64+d, j]   (blocks 0..31 — proven K2 body)
    if (blk < 32 && tid < 64) smem[tid] = ws[Q0_OFF + (blk >> 2) * 64 + tid];
    __syncthreads();
    if (blk < 32 && tid < 128) {
        int h = blk >> 2, j = (blk & 3) * 128 + tid;
        float acc = 0.f;
        #pragma unroll 8
        for (int d2 = 0; d2 < 64; ++d2)
            acc += smem[d2] * Wk[(size_t)(h * 64 + d2) * D_ + j];
        ws[TQ_OFF + h * D_ + j] = acc;
    }
    grid_barrier(bar, tgt); tgt += NB;

    // ---- P3: attn[b,h,s] = gate * exp(tq[h].x_s / 8)   (one s per wave; 2080 waves >= 2049)
    {
        int gw = blk * 8 + wv;
        const float4* t4 = (const float4*)(ws + TQ_OFF);
        for (int b = 0; b < B_; ++b) {
            if (gw < S_) {
                int s = gw;
                const float* xrow = (s == 0) ? ct : (nf + ((size_t)b * N_ + (s - 1)) * D_);
                const float4* x4 = (const float4*)xrow;
                float4 xa = x4[lane], xb = x4[64 + lane];
                float gate = 1.0f;
                if (s > 0) gate = (masks[b * N_ + s - 1] != 0.0f) ? 1.0f : 0.0f;
                float p[H_];
                #pragma unroll
                for (int h = 0; h < H_; ++h) {
                    float4 ta = t4[h * 128 + lane], tb = t4[h * 128 + 64 + lane];
                    p[h] = dot8(ta, xa, tb, xb);
                    p[h] = wave_allreduce_sum(p[h]);
                }
                if (lane == 0) {
                    #pragma unroll
                    for (int h = 0; h < H_; ++h)
                        ws[ATTN_OFF + (size_t)(b * H_ + h) * S_ + s] = gate * __expf(p[h] * 0.125f);
                }
            }
        }
    }
    grid_barrier(bar, tgt); tgt += NB;

    // ---- P4: chunk partial weighted sums (proven K4 body; block = chunk*4 + b, exact 1:1)
    {
        int chunk = blk >> 2, b = blk & 3;
        int s0 = chunk * SC;
        if (tid < 256) {                 // stage sa[h][ss] = smem[h*32+ss]
            int h = tid >> 5, ss = tid & 31;
            int s = s0 + ss;
            smem[tid] = (s < S_) ? ws[ATTN_OFF + (size_t)(b * H_ + h) * S_ + s] : 0.f;
        }
        __syncthreads();
        float acc[H_];
        #pragma unroll
        for (int h = 0; h < H_; ++h) acc[h] = 0.f;
        int smax = min(SC, S_ - s0);
        for (int ss = 0; ss < smax; ++ss) {
            int s = s0 + ss;
            const float* xrow = (s == 0) ? ct : (nf + ((size_t)b * N_ + (s - 1)) * D_);
            float xv = xrow[tid];
            #pragma unroll
            for (int h = 0; h < H_; ++h) acc[h] += smem[(h << 5) + ss] * xv;
        }
        size_t base = ((size_t)chunk * B_ + b) * H_;
        #pragma unroll
        for (int h = 0; h < H_; ++h)
            ws[PW_OFF + (base + h) * D_ + tid] = acc[h];
        if (tid < H_) {
            float z = 0.f;
            #pragma unroll 8
            for (int ss = 0; ss < SC; ++ss) z += smem[(tid << 5) + ss];
            ws[PZ_OFF + base + tid] = z;
        }
    }
    grid_barrier(bar, tgt); tgt += NB;

    // ---- P5: w[b,h,:] = (sum_c pw)/(sum_c pz) reduced into LDS, then o0 = Wv.w + bv
    //          blocks 0..255: bh = blk>>3 (8 blocks share one (b,h), redundant L2 reduce)
    if (blk < 256) {
        int bh = blk >> 3;               // b*8 + h
        int b = bh >> 3, h = bh & 7;
        float acc = 0.f;
        const float* pwp = ws + PW_OFF + (size_t)bh * D_ + tid;
        #pragma unroll 5
        for (int c = 0; c < NCH; ++c) acc += pwp[(size_t)c * (B_ * H_ * D_)];
        smem[tid] = acc;
        if (wv == 0) {                   // z = sum_c pz[c][b][h]
            float z = ws[PZ_OFF + lane * (B_ * H_) + bh];       // c = lane (0..63)
            if (lane == 0) z += ws[PZ_OFF + 64 * (B_ * H_) + bh]; // c = 64
            z = wave_allreduce_sum(z);
            if (lane == 0) smem[512] = z;
        }
        (void)b; (void)h;
    }
    __syncthreads();
    if (blk < 256) {
        int bh = blk >> 3, b = bh >> 3, h = bh & 7, sub = blk & 7;
        int r = h * 64 + sub * 8 + wv;
        const float4* wrow = (const float4*)smem;
        float4 wa = wrow[lane * 2], wb = wrow[lane * 2 + 1];
        const float4* row = (const float4*)(Wv + (size_t)r * D_);
        float4 a = row[lane * 2], c = row[lane * 2 + 1];
        float acc = dot8(a, wa, c, wb);
        acc = wave_reduce_sum(acc);
        if (lane == 0) ws[O0_OFF + b * D_ + r] = acc / smem[512] + bv[r];
    }
    grid_barrier(bar, tgt); tgt += NB;

    // ---- P6: y[b,r] = Wo[r,:].o0[b,:] + bo[r] + ct[r]   (blocks 0..255 — proven K7 body)
    if (blk < 256) {
        int b = blk >> 6;
        int r = (blk & 63) * 8 + wv;
        const float4* ov = (const float4*)(ws + O0_OFF + (size_t)b * D_);
        float4 oa = ov[lane * 2], ob = ov[lane * 2 + 1];
        const float4* row = (const float4*)(Wo + (size_t)r * D_);
        float4 a = row[lane * 2], c = row[lane * 2 + 1];
        float acc = dot8(a, oa, c, ob);
        acc = wave_reduce_sum(acc);
        if (lane == 0) ws[Y_OFF + b * D_ + r] = acc + bo[r] + ct[r];
    }
    grid_barrier(bar, tgt);

    // ---- P7: layernorm over D per batch (blocks 0..3 — proven K8 body)
    if (blk >= B_) return;
    {
        int b = blk;
        float v = ws[Y_OFF + b * D_ + tid];
        float s1 = v, s2 = v * v;
        #pragma unroll
        for (int off = 32; off > 0; off >>= 1) {
            s1 += __shfl_down(s1, off, 64);
            s2 += __shfl_down(s2, off, 64);
        }
        if (lane == 0) { smem[wv] = s1; smem[8 + wv] = s2; }
        __syncthreads();
        if (tid == 0) {
            float a = 0.f, c = 0.f;
            for (int i = 0; i < 8; ++i) { a += smem[i]; c += smem[8 + i]; }
            smem[0] = a; smem[8] = c;
        }
        __syncthreads();
        float mean = smem[0] * (1.0f / D_);
        float var  = smem[8] * (1.0f / D_) - mean * mean;
        float rinv = rsqrtf(var + 1e-5f);
        out[b * D_ + tid] = (v - mean) * rinv * gamma[tid] + beta[tid];
    }
}

extern "C" void kernel_launch(void* const* d_in, const int* in_sizes, int n_in,
                              void* d_out, int out_size, void* d_ws, size_t ws_size,
                              hipStream_t stream) {
    const float* nf    = (const float*)d_in[0];   // node_feat [B,N,D]
    // d_in[1] edge_weights, d_in[2] adj_matrix: not needed for CLS-row output
    const float* masks = (const float*)d_in[3];   // [B,N]
    const float* ct    = (const float*)d_in[4];   // [D]
    const float* Wq    = (const float*)d_in[5];
    const float* bq    = (const float*)d_in[6];
    const float* Wk    = (const float*)d_in[7];
    // d_in[8] bk dropped (softmax shift-invariance)
    const float* Wv    = (const float*)d_in[9];
    const float* bv    = (const float*)d_in[10];
    const float* Wo    = (const float*)d_in[11];
    const float* bo    = (const float*)d_in[12];
    const float* gamma = (const float*)d_in[13];
    const float* beta  = (const float*)d_in[14];
    float* ws  = (float*)d_ws;
    float* out = (float*)d_out;

    // workspace is re-poisoned between iterations -> barrier line must be re-zeroed.
    hipLaunchKernelGGL(init_kernel, dim3(1), dim3(64), 0, stream, ws);
    hipLaunchKernelGGL(fused_kernel, dim3(NB), dim3(512), 0, stream,
                       nf, ct, masks, Wq, bq, Wk, Wv, bv, Wo, bo, gamma, beta, ws, out);
}

// Round 2
// 234.157 us; speedup vs baseline: 1.3762x; 1.3762x over previous
//
#include <hip/hip_runtime.h>

#define B_ 4
#define N_ 2048
#define D_ 512
#define H_ 8
#define S_ (N_ + 1)          // 2049
#define SC 32                // s-rows per chunk
#define NCH 65               // ceil(2049/32)
#define NB  260              // grid = NCH*B_; 8 waves/block, all co-resident (proven R1)

// workspace layout (float offsets)
#define BAR_OFF  0                                  // [32] grid-barrier line (uint at [0])
#define TQ_OFF   64                                 // [H][D] = 4096
#define PW_OFF   8192                               // [NCH][B][H][D] = 1064960
#define PZ_OFF   (PW_OFF + NCH * B_ * H_ * D_)      // [NCH][B][H] = 2080
#define O0_OFF   (PZ_OFF + 2176)                    // [B][D]
#define Y_OFF    (O0_OFF + B_ * D_)                 // [B][D]

__device__ __forceinline__ float wave_reduce_sum(float v) {
    #pragma unroll
    for (int off = 32; off > 0; off >>= 1) v += __shfl_down(v, off, 64);
    return v;
}
__device__ __forceinline__ float wave_allreduce_sum(float v) {
    #pragma unroll
    for (int off = 1; off < 64; off <<= 1) v += __shfl_xor(v, off, 64);
    return v;
}
__device__ __forceinline__ float dot8(float4 a, float4 b, float4 c, float4 d) {
    return a.x*b.x + a.y*b.y + a.z*b.z + a.w*b.w
         + c.x*d.x + c.y*d.y + c.z*d.z + c.w*d.w;
}

// Grid barrier, fixed: release-add once, RELAXED spin (no per-poll cache
// invalidate!), single ACQUIRE load on exit (release-sequence of the RMW
// chain makes it synchronize with all adds). R1's version acquired in every
// poll iteration -> continuous L1/L2 invalidation storm -> ~25us/barrier.
__device__ __forceinline__ void grid_barrier(unsigned* bar, unsigned tgt) {
    __syncthreads();
    if (threadIdx.x == 0) {
        __hip_atomic_fetch_add(bar, 1u, __ATOMIC_RELEASE, __HIP_MEMORY_SCOPE_AGENT);
        while (__hip_atomic_load(bar, __ATOMIC_RELAXED, __HIP_MEMORY_SCOPE_AGENT) < tgt)
            __builtin_amdgcn_s_sleep(4);
        (void)__hip_atomic_load(bar, __ATOMIC_ACQUIRE, __HIP_MEMORY_SCOPE_AGENT);
    }
    __syncthreads();
}

__global__ void init_kernel(float* __restrict__ ws) {
    if (threadIdx.x < 32) ((unsigned*)ws)[BAR_OFF + threadIdx.x] = 0u;
}

__global__ void __launch_bounds__(512)
fused_kernel(const float* __restrict__ nf, const float* __restrict__ ct,
             const float* __restrict__ masks,
             const float* __restrict__ Wq, const float* __restrict__ bq,
             const float* __restrict__ Wk,
             const float* __restrict__ Wv, const float* __restrict__ bv,
             const float* __restrict__ Wo, const float* __restrict__ bo,
             const float* __restrict__ gamma, const float* __restrict__ beta,
             float* __restrict__ ws, float* __restrict__ out) {
    __shared__ float smem[544];          // union: q0slice[64] | sa[8][32] | w[512]+z | ln
    const int blk  = blockIdx.x;
    const int tid  = threadIdx.x;
    const int wv   = tid >> 6, lane = tid & 63;
    unsigned* bar  = (unsigned*)ws + BAR_OFF;
    unsigned  tgt  = NB;

    const int chunk = blk >> 2, b4 = blk & 3;   // Phase-B ownership, fixed for the block
    const int s0 = chunk * SC;

    // ---- P1: blocks 0..7 (h = blk): q0 slice block-locally, then tq[h,:].
    //          Merges old K1+K2 (one barrier saved): tq[h] only needs q0[h*64..h*64+63],
    //          which only needs the 64 matching Wq rows -> computable without a grid sync.
    if (blk < H_) {
        const int h = blk;
        const float4* c4 = (const float4*)ct;
        float4 ca = c4[lane * 2], cb = c4[lane * 2 + 1];
        #pragma unroll
        for (int i = 0; i < 8; ++i) {
            int rl = wv + 8 * i;                 // 0..63
            int r  = h * 64 + rl;
            const float4* row = (const float4*)(Wq + (size_t)r * D_);
            float4 a = row[lane * 2], b = row[lane * 2 + 1];
            float acc = dot8(a, ca, b, cb);
            acc = wave_reduce_sum(acc);
            if (lane == 0) smem[rl] = acc + bq[r];
        }
        __syncthreads();
        float acc = 0.f;
        #pragma unroll 8
        for (int d2 = 0; d2 < 64; ++d2)
            acc += smem[d2] * Wk[(size_t)(h * 64 + d2) * D_ + tid];
        ws[TQ_OFF + h * D_ + tid] = acc;
    } else {
        // idle blocks: warm own-XCD L2 with this block's Phase-B rows (overlaps P1)
        float sink = 0.f;
        for (int ss = wv; ss < SC; ss += 8) {
            int s = s0 + ss;
            if (s >= 1 && s <= N_) {
                const float4* x4 = (const float4*)(nf + ((size_t)b4 * N_ + (s - 1)) * D_);
                float4 xa = x4[lane], xb = x4[64 + lane];
                sink += xa.x + xb.w;
            }
        }
        asm volatile("" :: "v"(sink));       // keep prefetch live (rule #17)
    }
    grid_barrier(bar, tgt); tgt += NB;

    // ---- P2: fused scores+wsum per (chunk,b) — nf read ONCE from HBM.
    // B1: attn weights for the 32 own rows -> LDS sa[h][ss]  (proven K3 math)
    {
        const float4* t4 = (const float4*)(ws + TQ_OFF);
        #pragma unroll
        for (int i = 0; i < 4; ++i) {
            int ss = wv + 8 * i;                 // 0..31
            int s  = s0 + ss;
            if (s < S_) {
                const float* xrow = (s == 0) ? ct : (nf + ((size_t)b4 * N_ + (s - 1)) * D_);
                const float4* x4 = (const float4*)xrow;
                float4 xa = x4[lane], xb = x4[64 + lane];
                float gate = 1.0f;
                if (s > 0) gate = (masks[b4 * N_ + s - 1] != 0.0f) ? 1.0f : 0.0f;
                float p[H_];
                #pragma unroll
                for (int h = 0; h < H_; ++h) {
                    float4 ta = t4[h * 128 + lane], tb = t4[h * 128 + 64 + lane];
                    p[h] = dot8(ta, xa, tb, xb);
                    p[h] = wave_allreduce_sum(p[h]);
                }
                if (lane == 0) {
                    #pragma unroll
                    for (int h = 0; h < H_; ++h)
                        smem[(h << 5) + ss] = gate * __expf(p[h] * 0.125f);
                }
            } else if (lane == 0) {
                #pragma unroll
                for (int h = 0; h < H_; ++h) smem[(h << 5) + ss] = 0.f;
            }
        }
    }
    __syncthreads();
    // B2: weighted sums (proven K4 body; rows re-read hit own-XCD L2)
    {
        float acc[H_];
        #pragma unroll
        for (int h = 0; h < H_; ++h) acc[h] = 0.f;
        int smax = min(SC, S_ - s0);
        for (int ss = 0; ss < smax; ++ss) {
            int s = s0 + ss;
            const float* xrow = (s == 0) ? ct : (nf + ((size_t)b4 * N_ + (s - 1)) * D_);
            float xv = xrow[tid];
            #pragma unroll
            for (int h = 0; h < H_; ++h) acc[h] += smem[(h << 5) + ss] * xv;
        }
        size_t base = ((size_t)chunk * B_ + b4) * H_;
        #pragma unroll
        for (int h = 0; h < H_; ++h)
            ws[PW_OFF + (base + h) * D_ + tid] = acc[h];
        if (tid < H_) {
            float z = 0.f;
            #pragma unroll 8
            for (int ss = 0; ss < SC; ++ss) z += smem[(tid << 5) + ss];
            ws[PZ_OFF + base + tid] = z;
        }
    }
    grid_barrier(bar, tgt); tgt += NB;

    // ---- P3: w[b,h,:] = (sum_c pw)/(sum_c pz) into LDS, then o0 = Wv.w/z + bv
    //          (proven R1-P5 body; blocks 0..255, 8 blocks share one (b,h))
    if (blk < 256) {
        int bh = blk >> 3;
        float acc = 0.f;
        const float* pwp = ws + PW_OFF + (size_t)bh * D_ + tid;
        #pragma unroll 5
        for (int c = 0; c < NCH; ++c) acc += pwp[(size_t)c * (B_ * H_ * D_)];
        smem[tid] = acc;
        if (wv == 0) {
            float z = ws[PZ_OFF + lane * (B_ * H_) + bh];          // c = 0..63
            if (lane == 0) z += ws[PZ_OFF + 64 * (B_ * H_) + bh];  // c = 64
            z = wave_allreduce_sum(z);
            if (lane == 0) smem[512] = z;
        }
    }
    __syncthreads();
    if (blk < 256) {
        int bh = blk >> 3, b = bh >> 3, h = bh & 7, sub = blk & 7;
        int r = h * 64 + sub * 8 + wv;
        const float4* wrow = (const float4*)smem;
        float4 wa = wrow[lane * 2], wb = wrow[lane * 2 + 1];
        const float4* row = (const float4*)(Wv + (size_t)r * D_);
        float4 a = row[lane * 2], c = row[lane * 2 + 1];
        float acc = dot8(a, wa, c, wb);
        acc = wave_reduce_sum(acc);
        if (lane == 0) ws[O0_OFF + b * D_ + r] = acc / smem[512] + bv[r];
    }
    grid_barrier(bar, tgt); tgt += NB;

    // ---- P4: y[b,r] = Wo[r,:].o0[b,:] + bo[r] + ct[r]   (proven K7 body)
    if (blk < 256) {
        int b = blk >> 6;
        int r = (blk & 63) * 8 + wv;
        const float4* ov = (const float4*)(ws + O0_OFF + (size_t)b * D_);
        float4 oa = ov[lane * 2], ob = ov[lane * 2 + 1];
        const float4* row = (const float4*)(Wo + (size_t)r * D_);
        float4 a = row[lane * 2], c = row[lane * 2 + 1];
        float acc = dot8(a, oa, c, ob);
        acc = wave_reduce_sum(acc);
        if (lane == 0) ws[Y_OFF + b * D_ + r] = acc + bo[r] + ct[r];
    }
    grid_barrier(bar, tgt);

    // ---- P5: layernorm over D per batch (blocks 0..3 — proven K8 body)
    if (blk >= B_) return;
    {
        int b = blk;
        float v = ws[Y_OFF + b * D_ + tid];
        float s1 = v, s2 = v * v;
        #pragma unroll
        for (int off = 32; off > 0; off >>= 1) {
            s1 += __shfl_down(s1, off, 64);
            s2 += __shfl_down(s2, off, 64);
        }
        if (lane == 0) { smem[wv] = s1; smem[8 + wv] = s2; }
        __syncthreads();
        if (tid == 0) {
            float a = 0.f, c = 0.f;
            for (int i = 0; i < 8; ++i) { a += smem[i]; c += smem[8 + i]; }
            smem[0] = a; smem[8] = c;
        }
        __syncthreads();
        float mean = smem[0] * (1.0f / D_);
        float var  = smem[8] * (1.0f / D_) - mean * mean;
        float rinv = rsqrtf(var + 1e-5f);
        out[b * D_ + tid] = (v - mean) * rinv * gamma[tid] + beta[tid];
    }
}

extern "C" void kernel_launch(void* const* d_in, const int* in_sizes, int n_in,
                              void* d_out, int out_size, void* d_ws, size_t ws_size,
                              hipStream_t stream) {
    const float* nf    = (const float*)d_in[0];   // node_feat [B,N,D]
    // d_in[1] edge_weights, d_in[2] adj_matrix: not needed for CLS-row output
    const float* masks = (const float*)d_in[3];   // [B,N]
    const float* ct    = (const float*)d_in[4];   // [D]
    const float* Wq    = (const float*)d_in[5];
    const float* bq    = (const float*)d_in[6];
    const float* Wk    = (const float*)d_in[7];
    // d_in[8] bk dropped (softmax shift-invariance)
    const float* Wv    = (const float*)d_in[9];
    const float* bv    = (const float*)d_in[10];
    const float* Wo    = (const float*)d_in[11];
    const float* bo    = (const float*)d_in[12];
    const float* gamma = (const float*)d_in[13];
    const float* beta  = (const float*)d_in[14];
    float* ws  = (float*)d_ws;
    float* out = (float*)d_out;

    // workspace is re-poisoned between iterations -> barrier line must be re-zeroed.
    hipLaunchKernelGGL(init_kernel, dim3(1), dim3(64), 0, stream, ws);
    hipLaunchKernelGGL(fused_kernel, dim3(NB), dim3(512), 0, stream,
                       nf, ct, masks, Wq, bq, Wk, Wv, bv, Wo, bo, gamma, beta, ws, out);
}

// Round 3
// 191.489 us; speedup vs baseline: 1.6829x; 1.2228x over previous
//
#include <hip/hip_runtime.h>

#define B_ 4
#define N_ 2048
#define D_ 512
#define H_ 8
#define S_ (N_ + 1)          // 2049
#define SC 32                // s-rows per chunk
#define NCH 65               // ceil(2049/32)

// workspace layout (float offsets) — every cell written before read, no init needed
#define TQ_OFF   64                                 // [H][D] = 4096
#define PW_OFF   8192                               // [NCH][B][H][D] = 1064960
#define PZ_OFF   (PW_OFF + NCH * B_ * H_ * D_)      // [NCH][B][H] = 2080
#define O0_OFF   (PZ_OFF + 2176)                    // [B][D]
#define Y_OFF    (O0_OFF + B_ * D_)                 // [B][D]

__device__ __forceinline__ float wave_reduce_sum(float v) {
    #pragma unroll
    for (int off = 32; off > 0; off >>= 1) v += __shfl_down(v, off, 64);
    return v;
}
__device__ __forceinline__ float wave_allreduce_sum(float v) {
    #pragma unroll
    for (int off = 1; off < 64; off <<= 1) v += __shfl_xor(v, off, 64);
    return v;
}
__device__ __forceinline__ float dot8(float4 a, float4 b, float4 c, float4 d) {
    return a.x*b.x + a.y*b.y + a.z*b.z + a.w*b.w
         + c.x*d.x + c.y*d.y + c.z*d.z + c.w*d.w;
}

// ---- K1: blocks 0..31 (h=blk>>2, jq=blk&3): q0 slice (redundant x4) + tq quarter.
//          blocks 32..259: prefetch nf rows of same-linear-id K2 block into own-XCD L2.
__global__ void __launch_bounds__(512)
setup_kernel(const float* __restrict__ nf, const float* __restrict__ ct,
             const float* __restrict__ Wq, const float* __restrict__ bq,
             const float* __restrict__ Wk, float* __restrict__ ws) {
    __shared__ float q0s[64];
    __shared__ float part[4][128];
    const int blk = blockIdx.x;
    const int tid = threadIdx.x, wv = tid >> 6, lane = tid & 63;

    if (blk >= 32) {
        // prefetch: K2 block with same linear id owns chunk=blk>>2, b=blk&3
        int chunk = blk >> 2, b4 = blk & 3;
        int s0 = chunk * SC;
        float sink = 0.f;
        for (int ss = wv; ss < SC; ss += 8) {
            int s = s0 + ss;
            if (s >= 1 && s <= N_) {
                const float4* x4 = (const float4*)(nf + ((size_t)b4 * N_ + (s - 1)) * D_);
                float4 xa = x4[lane], xb = x4[64 + lane];
                sink += xa.x + xb.w;
            }
        }
        asm volatile("" :: "v"(sink));   // keep prefetch live (rule #17)
        return;
    }

    const int h = blk >> 2, jq = blk & 3;
    // q0 rows h*64..h*64+63 (proven R2-P1 body)
    const float4* c4 = (const float4*)ct;
    float4 ca = c4[lane * 2], cb = c4[lane * 2 + 1];
    #pragma unroll
    for (int i = 0; i < 8; ++i) {
        int rl = wv + 8 * i;                 // 0..63
        int r  = h * 64 + rl;
        const float4* row = (const float4*)(Wq + (size_t)r * D_);
        float4 a = row[lane * 2], b = row[lane * 2 + 1];
        float acc = dot8(a, ca, b, cb);
        acc = wave_reduce_sum(acc);
        if (lane == 0) q0s[rl] = acc + bq[r];
    }
    __syncthreads();
    // tq[h, jq*128 + jj] with 4-way d2 split across thread groups
    {
        int jj = tid & 127, g = tid >> 7;    // g = 0..3
        int j  = jq * 128 + jj;
        float acc = 0.f;
        #pragma unroll
        for (int d = 0; d < 16; ++d) {
            int d2 = g * 16 + d;
            acc += q0s[d2] * Wk[(size_t)(h * 64 + d2) * D_ + j];
        }
        part[g][jj] = acc;
    }
    __syncthreads();
    if (tid < 128)
        ws[TQ_OFF + h * D_ + jq * 128 + tid] =
            part[0][tid] + part[1][tid] + part[2][tid] + part[3][tid];
}

// ---- K2: fused scores+wsum per (chunk,b) — proven R2-P2 body, nf read once.
__global__ void __launch_bounds__(512)
scores_wsum_kernel(const float* __restrict__ nf, const float* __restrict__ ct,
                   const float* __restrict__ masks, float* __restrict__ ws) {
    __shared__ float sa[256];            // sa[h][ss] = sa[(h<<5)+ss]
    const int blk = blockIdx.x;
    const int tid = threadIdx.x, wv = tid >> 6, lane = tid & 63;
    const int chunk = blk >> 2, b4 = blk & 3;
    const int s0 = chunk * SC;

    // B1: attn weights for the 32 own rows -> LDS (proven K3 math)
    {
        const float4* t4 = (const float4*)(ws + TQ_OFF);
        #pragma unroll
        for (int i = 0; i < 4; ++i) {
            int ss = wv + 8 * i;             // 0..31
            int s  = s0 + ss;
            if (s < S_) {
                const float* xrow = (s == 0) ? ct : (nf + ((size_t)b4 * N_ + (s - 1)) * D_);
                const float4* x4 = (const float4*)xrow;
                float4 xa = x4[lane], xb = x4[64 + lane];
                float gate = 1.0f;
                if (s > 0) gate = (masks[b4 * N_ + s - 1] != 0.0f) ? 1.0f : 0.0f;
                float p[H_];
                #pragma unroll
                for (int h = 0; h < H_; ++h) {
                    float4 ta = t4[h * 128 + lane], tb = t4[h * 128 + 64 + lane];
                    p[h] = dot8(ta, xa, tb, xb);
                    p[h] = wave_allreduce_sum(p[h]);
                }
                if (lane == 0) {
                    #pragma unroll
                    for (int h = 0; h < H_; ++h)
                        sa[(h << 5) + ss] = gate * __expf(p[h] * 0.125f);
                }
            } else if (lane == 0) {
                #pragma unroll
                for (int h = 0; h < H_; ++h) sa[(h << 5) + ss] = 0.f;
            }
        }
    }
    __syncthreads();
    // B2: weighted sums (proven K4 body; rows re-read hit own-XCD L2)
    {
        float acc[H_];
        #pragma unroll
        for (int h = 0; h < H_; ++h) acc[h] = 0.f;
        int smax = min(SC, S_ - s0);
        for (int ss = 0; ss < smax; ++ss) {
            int s = s0 + ss;
            const float* xrow = (s == 0) ? ct : (nf + ((size_t)b4 * N_ + (s - 1)) * D_);
            float xv = xrow[tid];
            #pragma unroll
            for (int h = 0; h < H_; ++h) acc[h] += sa[(h << 5) + ss] * xv;
        }
        size_t base = ((size_t)chunk * B_ + b4) * H_;
        #pragma unroll
        for (int h = 0; h < H_; ++h)
            ws[PW_OFF + (base + h) * D_ + tid] = acc[h];
        if (tid < H_) {
            float z = 0.f;
            #pragma unroll 8
            for (int ss = 0; ss < SC; ++ss) z += sa[(tid << 5) + ss];
            ws[PZ_OFF + base + tid] = z;
        }
    }
}

// ---- K3: one block per (b,h): w = (sum_c pw)/(sum_c pz) into LDS, then
//          o0[b, h*64+rr] = Wv[r,:].w/z + bv[r] for the 64 own rows.
__global__ void __launch_bounds__(512)
reduce_wv_kernel(const float* __restrict__ Wv, const float* __restrict__ bv,
                 float* __restrict__ ws) {
    __shared__ float wsm[513];
    const int bh = blockIdx.x, b = bh >> 3, h = bh & 7;
    const int tid = threadIdx.x, wv = tid >> 6, lane = tid & 63;
    float acc = 0.f;
    const float* pwp = ws + PW_OFF + (size_t)bh * D_ + tid;
    #pragma unroll 5
    for (int c = 0; c < NCH; ++c) acc += pwp[(size_t)c * (B_ * H_ * D_)];
    wsm[tid] = acc;
    if (wv == 0) {
        float z = ws[PZ_OFF + lane * (B_ * H_) + bh];          // c = 0..63
        if (lane == 0) z += ws[PZ_OFF + 64 * (B_ * H_) + bh];  // c = 64
        z = wave_allreduce_sum(z);
        if (lane == 0) wsm[512] = z;
    }
    __syncthreads();
    float zinv = 1.0f / wsm[512];
    const float4* wrow = (const float4*)wsm;
    float4 wa = wrow[lane * 2], wb = wrow[lane * 2 + 1];
    #pragma unroll
    for (int i = 0; i < 8; ++i) {
        int r = h * 64 + wv + 8 * i;         // 64 own rows
        const float4* row = (const float4*)(Wv + (size_t)r * D_);
        float4 a = row[lane * 2], c = row[lane * 2 + 1];
        float acc2 = dot8(a, wa, c, wb);
        acc2 = wave_reduce_sum(acc2);
        if (lane == 0) ws[O0_OFF + b * D_ + r] = acc2 * zinv + bv[r];
    }
}

// ---- K4: y[b,r] = Wo[r,:].o0[b,:] + bo[r] + ct[r]   (round-0 body verbatim)
__global__ void wo_kernel(const float* __restrict__ Wo, const float* __restrict__ bo,
                          const float* __restrict__ ct, float* __restrict__ ws) {
    int b = blockIdx.x;
    int wv = threadIdx.x >> 6, lane = threadIdx.x & 63;
    int r = blockIdx.y * 4 + wv;
    const float4* ov = (const float4*)(ws + O0_OFF + (size_t)b * D_);
    float4 oa = ov[lane * 2], ob = ov[lane * 2 + 1];
    const float4* row = (const float4*)(Wo + (size_t)r * D_);
    float4 a = row[lane * 2], c = row[lane * 2 + 1];
    float acc = dot8(a, oa, c, ob);
    acc = wave_reduce_sum(acc);
    if (lane == 0) ws[Y_OFF + b * D_ + r] = acc + bo[r] + ct[r];
}

// ---- K5: layernorm over D per batch   (round-0 body verbatim)
__global__ void ln_kernel(const float* __restrict__ gamma, const float* __restrict__ beta,
                          const float* __restrict__ ws, float* __restrict__ out) {
    int b = blockIdx.x;
    int tid = threadIdx.x, wv = tid >> 6, lane = tid & 63;
    float v = ws[Y_OFF + b * D_ + tid];
    float s1 = v, s2 = v * v;
    #pragma unroll
    for (int off = 32; off > 0; off >>= 1) {
        s1 += __shfl_down(s1, off, 64);
        s2 += __shfl_down(s2, off, 64);
    }
    __shared__ float r1[8], r2[8];
    if (lane == 0) { r1[wv] = s1; r2[wv] = s2; }
    __syncthreads();
    if (tid == 0) {
        float a = 0.f, c = 0.f;
        for (int i = 0; i < 8; ++i) { a += r1[i]; c += r2[i]; }
        r1[0] = a; r2[0] = c;
    }
    __syncthreads();
    float mean = r1[0] * (1.0f / D_);
    float var  = r2[0] * (1.0f / D_) - mean * mean;
    float rinv = rsqrtf(var + 1e-5f);
    out[b * D_ + tid] = (v - mean) * rinv * gamma[tid] + beta[tid];
}

extern "C" void kernel_launch(void* const* d_in, const int* in_sizes, int n_in,
                              void* d_out, int out_size, void* d_ws, size_t ws_size,
                              hipStream_t stream) {
    const float* nf    = (const float*)d_in[0];   // node_feat [B,N,D]
    // d_in[1] edge_weights, d_in[2] adj_matrix: not needed for CLS-row output
    const float* masks = (const float*)d_in[3];   // [B,N]
    const float* ct    = (const float*)d_in[4];   // [D]
    const float* Wq    = (const float*)d_in[5];
    const float* bq    = (const float*)d_in[6];
    const float* Wk    = (const float*)d_in[7];
    // d_in[8] bk dropped (softmax shift-invariance)
    const float* Wv    = (const float*)d_in[9];
    const float* bv    = (const float*)d_in[10];
    const float* Wo    = (const float*)d_in[11];
    const float* bo    = (const float*)d_in[12];
    const float* gamma = (const float*)d_in[13];
    const float* beta  = (const float*)d_in[14];
    float* ws  = (float*)d_ws;
    float* out = (float*)d_out;

    // kernel boundaries are the barriers: no in-kernel grid sync, no atomics, no init.
    hipLaunchKernelGGL(setup_kernel,       dim3(260),      dim3(512), 0, stream, nf, ct, Wq, bq, Wk, ws);
    hipLaunchKernelGGL(scores_wsum_kernel, dim3(260),      dim3(512), 0, stream, nf, ct, masks, ws);
    hipLaunchKernelGGL(reduce_wv_kernel,   dim3(32),       dim3(512), 0, stream, Wv, bv, ws);
    hipLaunchKernelGGL(wo_kernel,          dim3(B_, 128),  dim3(256), 0, stream, Wo, bo, ct, ws);
    hipLaunchKernelGGL(ln_kernel,          dim3(B_),       dim3(512), 0, stream, gamma, beta, ws, out);
}